// Round 3
// baseline (446.572 us; speedup 1.0000x reference)
//
#include <hip/hip_runtime.h>
#include <math.h>

// Problem constants (match reference)
#define DIM_EMB 1024
#define TIMESTEP 4096
#define BATCH 16

// out[b,t,c] = x[b,t,c] * 32 + pe[t,c]
// pe[t,c] = sin(t * 10000^(-2c/D)) for even c, cos(...) for odd c.
// Memory-bound streaming op: 268 MB read + 268 MB write (mandatory).
// One block per t-row; each thread owns one float4 column slot, computes its
// 4 PE values once (8 transcendentals), then loops over the 16 batches.
// Per unroll step the whole 4096-block grid sweeps exactly one contiguous
// 16 MiB batch — globally coalesced. Non-temporal load/store (nt flag):
// read-once/write-once stream, skip L2 retention.

// Native clang vector type — __builtin_nontemporal_* rejects HIP_vector_type.
typedef float v4f __attribute__((ext_vector_type(4)));

__global__ __launch_bounds__(256)
void Pos_embedding_39161511805397_kernel(const float* __restrict__ x,
                                         float* __restrict__ out) {
    const int t   = blockIdx.x;       // 0..TIMESTEP-1
    const int tid = threadIdx.x;      // 0..255
    const int c0  = tid << 2;         // column of .x component (even)

    const float pos = (float)t;
    // 10000^(-2c/D) = exp2( -log2(10000)/(D/2) * c )
    const float k = -13.287712379549449f / 512.0f;
    const float a0 = pos * exp2f(k * (float)(c0 + 0));
    const float a1 = pos * exp2f(k * (float)(c0 + 1));
    const float a2 = pos * exp2f(k * (float)(c0 + 2));
    const float a3 = pos * exp2f(k * (float)(c0 + 3));

    v4f pe;
    pe.x = sinf(a0);   // even col
    pe.y = cosf(a1);   // odd col
    pe.z = sinf(a2);   // even col
    pe.w = cosf(a3);   // odd col

    const float s = 32.0f;  // sqrt(1024), exact

    const v4f* __restrict__ xv = (const v4f*)x;
    v4f* __restrict__ ov       = (v4f*)out;

    size_t idx = ((size_t)t * DIM_EMB + (size_t)c0) >> 2;          // float4 units
    const size_t stride = ((size_t)TIMESTEP * DIM_EMB) >> 2;       // per batch

    #pragma unroll
    for (int b = 0; b < BATCH; ++b) {
        v4f v = __builtin_nontemporal_load(&xv[idx]);
        v = v * s + pe;
        __builtin_nontemporal_store(v, &ov[idx]);
        idx += stride;
    }
}

extern "C" void kernel_launch(void* const* d_in, const int* in_sizes, int n_in,
                              void* d_out, int out_size, void* d_ws, size_t ws_size,
                              hipStream_t stream) {
    const float* x = (const float*)d_in[0];
    float* out     = (float*)d_out;
    dim3 grid(TIMESTEP);
    dim3 block(256);
    Pos_embedding_39161511805397_kernel<<<grid, block, 0, stream>>>(x, out);
}